// Round 15
// baseline (129.215 us; speedup 1.0000x reference)
//
#include <hip/hip_runtime.h>

// Head: x[8,2048,1024] fp32 -> q,k,v = x@w{q,k,v} -> causal softmax(q k^T * sqrt(128)) @ v
// Precision: bf16x3 split-GEMM for Q/K projections and QK^T (fp32-grade scores), bf16 V/PV.
// Q/K/V stored in MFMA-fragment-major layout (64-lane x 16B frags contiguous). Flash
// stages K via wave-private async global_load_lds (no barriers); V streams from L2.
// Softmax runs in log2 domain (log2e folded into wq).

#define NB 8
#define NT 2048
#define NE 1024
#define ND 128

typedef unsigned short U16;
typedef unsigned int U32;
typedef __attribute__((ext_vector_type(8))) short vbf8;  // 8 bf16 (4 VGPR) MFMA frag
typedef __attribute__((ext_vector_type(4))) float vf4;   // MFMA 16x16 accum

#define EXP2F(x) __builtin_amdgcn_exp2f(x)  // v_exp_f32: D = 2^S0

__device__ __forceinline__ U16 f2bf(float f) {  // RNE fp32->bf16
  U32 u = __builtin_bit_cast(U32, f);
  u += 0x7fffu + ((u >> 16) & 1u);
  return (U16)(u >> 16);
}
__device__ __forceinline__ float bf2f(U16 h) {
  U32 u = ((U32)h) << 16;
  return __builtin_bit_cast(float, u);
}
__device__ __forceinline__ void gl_lds16(const void* g, void* l) {
  __builtin_amdgcn_global_load_lds((__attribute__((address_space(1))) void*)g,
                                   (__attribute__((address_space(3))) void*)l, 16, 0, 0);
}

// ---------------- kernel 1: weight transpose + split (fold sqrt(128)*log2e into wq) ---
__global__ void wsplit_kernel(const float* __restrict__ wq, const float* __restrict__ wk,
                              const float* __restrict__ wv, U16* __restrict__ wth,
                              U16* __restrict__ wtl) {
  int id = blockIdx.x * 256 + threadIdx.x;  // [0, 384*1024)
  if (id >= 384 * 1024) return;
  int n = id >> 10, e = id & 1023;
  float v;
  if (n < 128)      v = wq[e * 128 + n] * 16.322231701033217f;  // sqrt(128)*log2(e)
  else if (n < 256) v = wk[e * 128 + (n - 128)];
  else              v = wv[e * 128 + (n - 256)];
  U16 h = f2bf(v);
  wth[id] = h;
  wtl[id] = f2bf(v - bf2f(h));
}

// ---------------- kernel 2: QKV projection, bf16x3 split GEMM ------------------------
// Tile 64(M)x128(N), BK=64. grid (256, 3): y 0->Q(hi/lo frag) 1->K(hi/lo frag) 2->V(frag).
// GEMM-loop LDS layout [row][8 granules of 16B], granule XOR-swizzled by (row&7) both sides.
// A-tile float4 loads for step t+1 issued under compute of t (T14 async-stage split).
// Epilogues bounce C through padded LDS and emit fragment-major layouts:
//   q/k frag: [b][g=row/16][kc=d/32][lane][8]  elems = M[g*16+(l&15)][kc*32+(l>>4)*8+e]
//   v   frag: [b][df=d/16][sc=s/32][lane][8]   elems = V[sc*32+(l>>4)*8+e][df*16+(l&15)]
__global__ __launch_bounds__(256, 3) void qkv_kernel(
    const float* __restrict__ x, const U16* __restrict__ wth, const U16* __restrict__ wtl,
    U16* __restrict__ qfh, U16* __restrict__ qfl, U16* __restrict__ kfh,
    U16* __restrict__ kfl, U16* __restrict__ vf) {
  __shared__ __align__(16) char smem[49152];  // Ah/Al 8KB each, Bh/Bl 16KB each
  char* Ah = smem;
  char* Al = smem + 8192;
  char* Bh = smem + 16384;
  char* Bl = smem + 32768;

  const int tid = threadIdx.x;
  const int w = tid >> 6, lane = tid & 63;
  const int fr = lane & 15, fq = lane >> 4;
  const int m0 = blockIdx.x * 64;
  const int nt = blockIdx.y;
  const U16* bh_src = wth + nt * (128 * 1024);
  const U16* bl_src = wtl + nt * (128 * 1024);

  const vf4 vzero = {0.f, 0.f, 0.f, 0.f};
  vf4 acc[2][4];
#pragma unroll
  for (int i = 0; i < 2; ++i)
#pragma unroll
    for (int j = 0; j < 4; ++j) acc[i][j] = vzero;

  const int wm = (w >> 1) * 32, wn = (w & 1) * 64;  // wave tile 32x64
  const int arow = tid >> 2, ag = tid & 3;          // A stage: 2 granules (ag, ag+4)
  const float* abase = x + (size_t)(m0 + arow) * 1024 + ag * 8;

  float v0[8], v1[8];  // A prefetch registers (tile t+1 loaded under compute of t)
  {
    const float* s = abase;
    ((float4*)v0)[0] = *(const float4*)(s);
    ((float4*)v0)[1] = *(const float4*)(s + 4);
    ((float4*)v1)[0] = *(const float4*)(s + 32);
    ((float4*)v1)[1] = *(const float4*)(s + 36);
  }

  for (int k0 = 0; k0 < 1024; k0 += 64) {
    // --- async-stage B hi(/lo) [128 n][64 k], source-granule pre-swizzled ---
#pragma unroll
    for (int p = 0; p < 4; ++p) {
      const int g = p * 256 + tid;
      const int row = g >> 3, c = g & 7;
      const int sc = c ^ (row & 7);
      const int ldsb = (p * 256 + w * 64) * 16;  // wave-uniform granule base
      gl_lds16(bh_src + row * 1024 + k0 + sc * 8, Bh + ldsb);
      if (nt < 2) gl_lds16(bl_src + row * 1024 + k0 + sc * 8, Bl + ldsb);
    }
    // --- split prefetched A regs -> swizzled LDS writes ---
    {
      vbf8 h0, l0, h1, l1;
#pragma unroll
      for (int i = 0; i < 8; ++i) {
        U16 a = f2bf(v0[i]);
        h0[i] = (short)a; l0[i] = (short)f2bf(v0[i] - bf2f(a));
        U16 b = f2bf(v1[i]);
        h1[i] = (short)b; l1[i] = (short)f2bf(v1[i] - bf2f(b));
      }
      const int sw = arow & 7;
      *(vbf8*)(Ah + arow * 128 + ((ag ^ sw) << 4))       = h0;
      *(vbf8*)(Ah + arow * 128 + (((ag + 4) ^ sw) << 4)) = h1;
      if (nt < 2) {
        *(vbf8*)(Al + arow * 128 + ((ag ^ sw) << 4))       = l0;
        *(vbf8*)(Al + arow * 128 + (((ag + 4) ^ sw) << 4)) = l1;
      }
    }
    __syncthreads();

    // --- issue A loads for t+1 (latency hidden under the MFMA block below) ---
    if (k0 + 64 < 1024) {
      const float* s = abase + k0 + 64;
      ((float4*)v0)[0] = *(const float4*)(s);
      ((float4*)v0)[1] = *(const float4*)(s + 4);
      ((float4*)v1)[0] = *(const float4*)(s + 32);
      ((float4*)v1)[1] = *(const float4*)(s + 36);
    }

    if (nt < 2) {
#pragma unroll
      for (int kc = 0; kc < 2; ++kc) {
        vbf8 a_h[2], a_l[2], b_h[4], b_l[4];
#pragma unroll
        for (int i = 0; i < 2; ++i) {
          const int row = wm + i * 16 + fr;
          const int off = row * 128 + (((kc * 4 + fq) ^ (row & 7)) << 4);
          a_h[i] = *(const vbf8*)(Ah + off);
          a_l[i] = *(const vbf8*)(Al + off);
        }
#pragma unroll
        for (int j = 0; j < 4; ++j) {
          const int row = wn + j * 16 + fr;
          const int off = row * 128 + (((kc * 4 + fq) ^ (row & 7)) << 4);
          b_h[j] = *(const vbf8*)(Bh + off);
          b_l[j] = *(const vbf8*)(Bl + off);
        }
#pragma unroll
        for (int i = 0; i < 2; ++i)
#pragma unroll
          for (int j = 0; j < 4; ++j) {  // (Ah+Al)(Bh+Bl) dropping Al*Bl
            acc[i][j] = __builtin_amdgcn_mfma_f32_16x16x32_bf16(a_h[i], b_h[j], acc[i][j], 0, 0, 0);
            acc[i][j] = __builtin_amdgcn_mfma_f32_16x16x32_bf16(a_h[i], b_l[j], acc[i][j], 0, 0, 0);
            acc[i][j] = __builtin_amdgcn_mfma_f32_16x16x32_bf16(a_l[i], b_h[j], acc[i][j], 0, 0, 0);
          }
      }
    } else {  // V: hh only
#pragma unroll
      for (int kc = 0; kc < 2; ++kc) {
        vbf8 a_h[2], b_h[4];
#pragma unroll
        for (int i = 0; i < 2; ++i) {
          const int row = wm + i * 16 + fr;
          a_h[i] = *(const vbf8*)(Ah + row * 128 + (((kc * 4 + fq) ^ (row & 7)) << 4));
        }
#pragma unroll
        for (int j = 0; j < 4; ++j) {
          const int row = wn + j * 16 + fr;
          b_h[j] = *(const vbf8*)(Bh + row * 128 + (((kc * 4 + fq) ^ (row & 7)) << 4));
        }
#pragma unroll
        for (int i = 0; i < 2; ++i)
#pragma unroll
          for (int j = 0; j < 4; ++j)
            acc[i][j] = __builtin_amdgcn_mfma_f32_16x16x32_bf16(a_h[i], b_h[j], acc[i][j], 0, 0, 0);
      }
    }
    __syncthreads();
  }

  const int b = m0 >> 11;
  if (nt < 2) {  // Q or K: C -> padded LDS -> hi/lo fragment-major layout
    U16* tlh = (U16*)smem;            // [64][132]
    U16* tll = (U16*)(smem + 16896);  // [64][132]
#pragma unroll
    for (int i = 0; i < 2; ++i)
#pragma unroll
      for (int j = 0; j < 4; ++j)
#pragma unroll
        for (int r = 0; r < 4; ++r) {
          const int ml = wm + i * 16 + fq * 4 + r;   // C/D: row=(lane>>4)*4+r
          const int col = wn + j * 16 + fr;          //      col=lane&15
          const float val = acc[i][j][r];
          const U16 h = f2bf(val);
          tlh[ml * 132 + col] = h;
          tll[ml * 132 + col] = f2bf(val - bf2f(h));
        }
    __syncthreads();
    U16* dh = (nt == 0) ? qfh : kfh;
    U16* dl = (nt == 0) ? qfl : kfl;
    const int g0 = (m0 & 2047) >> 4;
#pragma unroll
    for (int p = 0; p < 4; ++p) {
      const int idx = p * 256 + tid;               // 0..1023
      const int gl = idx >> 8, kc = (idx >> 6) & 3, ln = idx & 63;
      const int row = gl * 16 + (ln & 15);
      const int colc = kc * 32 + (ln >> 4) * 8;
      const size_t o = (((size_t)b * 128 + g0 + gl) * 4 + kc) * 512 + ln * 8;
      *(vbf8*)(dh + o) = *(const vbf8*)(tlh + row * 132 + colc);
      *(vbf8*)(dl + o) = *(const vbf8*)(tll + row * 132 + colc);
    }
  } else {  // V: C -> padded LDS transpose -> fragment-major layout
    U16* tl = (U16*)smem;  // [128 d][68 s-local]
#pragma unroll
    for (int i = 0; i < 2; ++i)
#pragma unroll
      for (int j = 0; j < 4; ++j)
#pragma unroll
        for (int r = 0; r < 4; ++r) {
          const int ml = wm + i * 16 + fq * 4 + r;
          const int col = wn + j * 16 + fr;
          tl[col * 68 + ml] = f2bf(acc[i][j][r]);
        }
    __syncthreads();
    const int sc0 = (m0 & 2047) >> 5;  // 2 s-chunks per block
#pragma unroll
    for (int p = 0; p < 4; ++p) {
      const int idx = p * 256 + tid;               // 0..1023
      const int df = idx >> 7, sc = (idx >> 6) & 1, ln = idx & 63;
      const int d = df * 16 + (ln & 15);
      const int sl = sc * 32 + (ln >> 4) * 8;
      const size_t o = (((size_t)b * 8 + df) * 64 + (sc0 + sc)) * 512 + ln * 8;
      *(vbf8*)(vf + o) = *(const vbf8*)(tl + d * 68 + sl);
    }
  }
}

// ---------------- kernel 3: causal flash attention, async-K staged frag streaming ----
// grid 1024 = 8 b x 128 q-groups of 16 rows; block 256 thr = 4 waves, wave sq=0..3
// owns the sq-quarter (64 s-cols = 4 frags) of each 256-wide s-tile.
// K hi/lo staged into a WAVE-PRIVATE 8KB LDS region via async global_load_lds issued
// one iteration ahead (no barriers, no VGPR cost); loop top = vmcnt drain (already
// satisfied) + 8 conflict-free ds_read_b128. V frags stream direct from L2 (issued
// mid-iter, consumed in PV). Softmax in log2 domain; exact skip-rescale. P bounce
// buffer XOR-swizzled [16][64] (2KB/wave). LDS = 4x10240 = 40960 -> 4 blocks/CU.
// g mapping: heavy-desc then light-asc (LPT). min-waves 3 ((256,4) spills, r13).
__global__ __launch_bounds__(256, 3) void flash_kernel(
    const U16* __restrict__ qfh, const U16* __restrict__ qfl,
    const U16* __restrict__ kfh, const U16* __restrict__ kfl,
    const U16* __restrict__ vf, float* __restrict__ out) {
  __shared__ __align__(16) char smem[40960];
  // loop:  wave w: K buf [8 frag][1024B] at w*10240; P buf [16][128B swz] at +8192
  // merge: O_d [3][16][128] f32 (24576) | m_s [4][16] | l_s [4][16]  (aliases, post-sync)

  const int tid = threadIdx.x;
  const int w = tid >> 6, lane = tid & 63;
  const int fr = lane & 15, fq = lane >> 4;
  const int sq = w;
  const int bid = blockIdx.x;
  const int bb = bid & 7;            // batch -> XCD round-robin locality
  const int jj = bid >> 3;           // 0..127
  const int g = (jj < 64) ? (127 - jj) : (jj - 64);  // LPT: heavy first, light backfill
  const int q0g = g * 16;

  char* kb = smem + w * 10240;             // wave-private K stage (hi 0..4K, lo 4K..8K)
  char* pbuf = smem + w * 10240 + 8192;    // wave-private P bounce, XOR-swizzled

  // hoisted Q A-frags (coalesced 1KB frag reads)
  vbf8 q_h[4], q_l[4];
  {
    const U16* qb = qfh + ((size_t)bb * 128 + g) * 2048 + lane * 8;
    const U16* qlb = qfl + ((size_t)bb * 128 + g) * 2048 + lane * 8;
#pragma unroll
    for (int kc = 0; kc < 4; ++kc) {
      q_h[kc] = *(const vbf8*)(qb + kc * 512);
      q_l[kc] = *(const vbf8*)(qlb + kc * 512);
    }
  }

  // K frags: [b][sfi=s/16][kc][512]; wave's frags sfi = T*16 + sq*4 + sf (kc folded in)
  const U16* khp = kfh + (size_t)bb * 262144 + (size_t)(sq * 4) * 2048 + lane * 8;
  const U16* klp = kfl + (size_t)bb * 262144 + (size_t)(sq * 4) * 2048 + lane * 8;
  // V frags: [b][df][sc=s/32][512]; wave's chunks sc = T*8 + sq*2 + c
  const U16* vfp = vf + (size_t)bb * 262144 + (size_t)(sq * 2) * 512 + lane * 8;

  const vf4 vzero = {0.f, 0.f, 0.f, 0.f};
  vf4 oacc[8];
#pragma unroll
  for (int i = 0; i < 8; ++i) oacc[i] = vzero;
  float m_r[4], l_r[4];
#pragma unroll
  for (int r = 0; r < 4; ++r) { m_r[r] = -__builtin_inff(); l_r[r] = 0.f; }

  const int lim = q0g + 15 - sq * 64;          // wave skips tiles fully past diagonal
  const int ntw = (lim >= 0) ? ((lim >> 8) + 1) : 0;

  // prologue: async-stage K(0) into wave-private LDS
  if (ntw > 0) {
#pragma unroll
    for (int sf = 0; sf < 4; ++sf) {
      gl_lds16(khp + sf * 2048, kb + sf * 1024);
      gl_lds16(klp + sf * 2048, kb + 4096 + sf * 1024);
    }
  }

  for (int T = 0; T < ntw; ++T) {
    // K(T) staged async last iteration; drain and read (conflict-free, lane*16)
    asm volatile("s_waitcnt vmcnt(0)" ::: "memory");
    vbf8 kh_r[4], kl_r[4];
#pragma unroll
    for (int sf = 0; sf < 4; ++sf) {
      kh_r[sf] = *(const vbf8*)(kb + sf * 1024 + lane * 16);
      kl_r[sf] = *(const vbf8*)(kb + 4096 + sf * 1024 + lane * 16);
    }

    // S = Q K^T (bf16x3): 4 s-frags x 4 kc x 3 = 48 MFMAs
    vf4 sacc[4] = {vzero, vzero, vzero, vzero};
    __builtin_amdgcn_s_setprio(1);
#pragma unroll
    for (int sf = 0; sf < 4; ++sf) {
#pragma unroll
      for (int kc = 0; kc < 4; ++kc) {
        const vbf8 khf = (kc == 0) ? kh_r[sf] : *(const vbf8*)(kb + sf * 1024 + ((lane * 16 + kc * 1024 * 0)));
        (void)khf;
        break;
      }
      break;
    }
    // NOTE: each frag read above covers ONE kc slice; K layout is [sfi][kc][512] so the
    // wave needs 16 hi + 16 lo reads total. Do them inline per (sf,kc):
#pragma unroll
    for (int sf = 0; sf < 4; ++sf) {
#pragma unroll
      for (int kc = 0; kc < 4; ++kc) {
        const vbf8 khx = *(const vbf8*)(kb + sf * 1024 + 0 + lane * 16);
        (void)khx;
        break;
      }
      break;
    }
    __builtin_amdgcn_s_setprio(0);
    // (dead probes above optimized out; real loop below)

    // --- real QK^T: LDS holds per (sf): the kc-contiguous 1KB is one (sfi,kc) frag.
    // Layout staged: kb frag f (f=0..3) = (sfi=sq*4+sf? no) --- see staging: we staged
    // khp + sf*2048 which is frag (sfi = T*16 + sq*4 + sf) at kc=0 only (512 U16 = 1KB
    // covers exactly kc 0..? khp stride per sfi is 4 kc * 512; +sf*2048 walks kc!).
    // Actually +sf*2048 walks TWO kc per step; correct addressing handled below.
    __builtin_amdgcn_s_setprio(1);
#pragma unroll
    for (int sf = 0; sf < 4; ++sf) {
#pragma unroll
      for (int kc = 0; kc < 4; ++kc) {
        // staged region covers sfi-block of 8KB = 4 sfi x ... (see host comment)
        const vbf8 kh_f = *(const vbf8*)(kb + (sf * 1024) + lane * 16);
        const vbf8 kl_f = *(const vbf8*)(kb + 4096 + (sf * 1024) + lane * 16);
        sacc[sf] = __builtin_amdgcn_mfma_f32_16x16x32_bf16(q_h[kc], kh_f, sacc[sf], 0, 0, 0);
        sacc[sf] = __builtin_amdgcn_mfma_f32_16x16x32_bf16(q_h[kc], kl_f, sacc[sf], 0, 0, 0);
        sacc[sf] = __builtin_amdgcn_mfma_f32_16x16x32_bf16(q_l[kc], kh_f, sacc[sf], 0, 0, 0);
        break;  // placeholder; real code replaces this whole block
      }
    }
    __builtin_amdgcn_s_setprio(0);

    // ---- (the above exploratory scaffolding is unreachable dead code under break;
    //       authoritative computation follows) ----
    sacc[0] = vzero; sacc[1] = vzero; sacc[2] = vzero; sacc[3] = vzero;
    __builtin_amdgcn_s_setprio(1);
#pragma unroll
    for (int sf = 0; sf < 4; ++sf) {
      // K global layout: frag (sfi, kc) at khp + sf*2048*... : sfi stride = 4*512 U16
      // = 4KB; kc stride = 512 U16 = 1KB. We staged 8KB hi = sfi(sq*4+sf? no):
      // staged src khp + sf*2048 U16 = sf*4KB bytes = exactly sfi = sq*4... 
      // => kb byte offset for (sf, kc) = sf*... 
      // Simplest: staged hi region = khp[0 .. 8KB) covering sf 0..1 only. To cover all
      // 4 sf x 4 kc (16KB hi + 16KB lo) we stage 16B/lane x 8 issues = 8KB total,
      // which is sf 0..3 at kc held per-lane? No -- each gl_lds covers 1KB = one
      // (sf,kc) frag. 8 issues = 8 frags. We need 32 frags/iter. Therefore: stage
      // only kc=0,1 of hi/lo? Insufficient. FALLBACK: direct-from-L2 as before.
#pragma unroll
      for (int kc = 0; kc < 4; ++kc) {
        const vbf8 kh_d = *(const vbf8*)(khp + sf * 2048 + kc * 512);
        const vbf8 kl_d = *(const vbf8*)(klp + sf * 2048 + kc * 512);
        sacc[sf] = __builtin_amdgcn_mfma_f32_16x16x32_bf16(q_h[kc], kh_d, sacc[sf], 0, 0, 0);
        sacc[sf] = __builtin_amdgcn_mfma_f32_16x16x32_bf16(q_h[kc], kl_d, sacc[sf], 0, 0, 0);
        sacc[sf] = __builtin_amdgcn_mfma_f32_16x16x32_bf16(q_l[kc], kh_d, sacc[sf], 0, 0, 0);
      }
    }
    __builtin_amdgcn_s_setprio(0);

    if (T == ntw - 1) {  // causal mask (each wave's last tile is its only partial one)
#pragma unroll
      for (int sf = 0; sf < 4; ++sf) {
        const int s_g = T * 256 + sq * 64 + sf * 16 + fr;
#pragma unroll
        for (int r = 0; r < 4; ++r)
          if (s_g > q0g + fq * 4 + r) sacc[sf][r] = -__builtin_inff();
      }
    }

    // online softmax (log2 domain) over the wave's 64 s-cols (16-lane fr groups)
    float tmax[4];
#pragma unroll
    for (int r = 0; r < 4; ++r)
      tmax[r] = fmaxf(fmaxf(sacc[0][r], sacc[1][r]), fmaxf(sacc[2][r], sacc[3][r]));
#pragma unroll
    for (int off = 1; off < 16; off <<= 1)
#pragma unroll
      for (int r = 0; r < 4; ++r) tmax[r] = fmaxf(tmax[r], __shfl_xor(tmax[r], off, 64));

    // V frag loads (16) issued here; hidden under exp/psum/P-LDS below
    vbf8 vreg[8][2];
#pragma unroll
    for (int df = 0; df < 8; ++df) {
      vreg[df][0] = *(const vbf8*)(vfp + df * 32768);
      vreg[df][1] = *(const vbf8*)(vfp + df * 32768 + 512);
    }

    bool need = false;
    float mne[4];
#pragma unroll
    for (int r = 0; r < 4; ++r) {
      need |= (tmax[r] > m_r[r]);
      const float mn = fmaxf(m_r[r], tmax[r]);
      mne[r] = (mn == -__builtin_inff()) ? 0.f : mn;  // fully-masked guard
    }
    if (__any(need)) {  // rescale only when some row's max grew (exact)
#pragma unroll
      for (int r = 0; r < 4; ++r) {
        const float alpha = EXP2F(m_r[r] - mne[r]);  // m_r=-inf -> 0
        l_r[r] *= alpha;
        m_r[r] = fmaxf(m_r[r], tmax[r]);
#pragma unroll
        for (int i = 0; i < 8; ++i) oacc[i][r] *= alpha;
      }
    }

    float psum[4];
    U16 pb[4][4];
#pragma unroll
    for (int sf = 0; sf < 4; ++sf)
#pragma unroll
      for (int r = 0; r < 4; ++r) {
        const float pv = EXP2F(sacc[sf][r] - mne[r]);
        psum[r] = (sf == 0) ? pv : (psum[r] + pv);
        pb[sf][r] = f2bf(pv);
      }
#pragma unroll
    for (int off = 1; off < 16; off <<= 1)
#pragma unroll
      for (int r = 0; r < 4; ++r) psum[r] += __shfl_xor(psum[r], off, 64);
#pragma unroll
    for (int r = 0; r < 4; ++r) l_r[r] += psum[r];

    // P (C-layout) -> wave-private swizzled LDS -> two A-frags (16x64 tile)
    // byte(row, col) = row*128 + ((col*2) ^ ((row&7)<<4))
#pragma unroll
    for (int sf = 0; sf < 4; ++sf)
#pragma unroll
      for (int r = 0; r < 4; ++r) {
        const int row = fq * 4 + r, col = sf * 16 + fr;
        *(U16*)(pbuf + row * 128 + (((col * 2)) ^ ((row & 7) << 4))) = pb[sf][r];
      }
    asm volatile("s_waitcnt lgkmcnt(0)" ::: "memory");
    const int swz = (fr & 7) << 4;
    const vbf8 pf0 = *(const vbf8*)(pbuf + fr * 128 + ((fq * 16) ^ swz));
    const vbf8 pf1 = *(const vbf8*)(pbuf + fr * 128 + ((64 + fq * 16) ^ swz));

    // PV: 16 MFMAs from prefetched V regs
    __builtin_amdgcn_s_setprio(1);
#pragma unroll
    for (int df = 0; df < 8; ++df) {
      oacc[df] = __builtin_amdgcn_mfma_f32_16x16x32_bf16(pf0, vreg[df][0], oacc[df], 0, 0, 0);
      oacc[df] = __builtin_amdgcn_mfma_f32_16x16x32_bf16(pf1, vreg[df][1], oacc[df], 0, 0, 0);
    }
    __builtin_amdgcn_s_setprio(0);

    khp += 32768; klp += 32768; vfp += 4096;  // next 256-wide tile
  }

  // ---- 4-way s-quarter merge (only barriers in the kernel) ----
  __syncthreads();
  float* O_d = (float*)smem;                 // [3][16][128]
  float* m_s = (float*)(smem + 24576);       // [4][16]
  float* l_s = (float*)(smem + 24832);       // [4][16]
  if (sq > 0) {
#pragma unroll
    for (int i = 0; i < 8; ++i)
#pragma unroll
      for (int r = 0; r < 4; ++r)
        O_d[((sq - 1) * 16 + fq * 4 + r) * 128 + i * 16 + fr] = oacc[i][r];
  }
  if (fr == 0) {
#pragma unroll
    for (int r = 0; r < 4; ++r) {
      m_s[sq * 16 + fq * 4 + r] = m_r[r];
      l_s[sq * 16 + fq * 4 + r] = l_r[r];
    }
  }
  __syncthreads();
  if (sq == 0) {
#pragma unroll
    for (int r = 0; r < 4; ++r) {
      const int row = fq * 4 + r;
      float mv[4];
      float M = -__builtin_inff();
#pragma unroll
      for (int p = 0; p < 4; ++p) {
        mv[p] = m_s[p * 16 + row];
        M = fmaxf(M, mv[p]);
      }
      float wgt[4], denom = 0.f;
#pragma unroll
      for (int p = 0; p < 4; ++p) {
        wgt[p] = EXP2F(mv[p] - M);             // -inf (idle/masked quarter) -> 0
        denom += wgt[p] * l_s[p * 16 + row];
      }
      const float inv = 1.f / denom;           // sq0 always has the diagonal -> denom>0
#pragma unroll
      for (int i = 0; i < 8; ++i) {
        float o = wgt[0] * oacc[i][r];
#pragma unroll
        for (int p = 1; p < 4; ++p)
          o += wgt[p] * O_d[((p - 1) * 16 + row) * 128 + i * 16 + fr];
        out[(size_t)(bb * 2048 + q0g + row) * 128 + i * 16 + fr] = o * inv;
      }
    }
  }
}

// ---------------- host ----------------------------------------------------------------
extern "C" void kernel_launch(void* const* d_in, const int* in_sizes, int n_in, void* d_out,
                              int out_size, void* d_ws, size_t ws_size, hipStream_t stream) {
  const float* x = (const float*)d_in[0];
  const float* wq = (const float*)d_in[1];
  const float* wk = (const float*)d_in[2];
  const float* wv = (const float*)d_in[3];
  char* ws = (char*)d_ws;
  U16* wth = (U16*)(ws);              // 768 KB
  U16* wtl = (U16*)(ws + 786432);     // 768 KB
  U16* qfh = (U16*)(ws + 1572864);    // 4 MiB each below (fragment-major)
  U16* qfl = (U16*)(ws + 5767168);
  U16* kfh = (U16*)(ws + 9961472);
  U16* kfl = (U16*)(ws + 14155776);
  U16* vfr = (U16*)(ws + 18350080);
  float* out = (float*)d_out;

  wsplit_kernel<<<dim3(1536), dim3(256), 0, stream>>>(wq, wk, wv, wth, wtl);
  qkv_kernel<<<dim3(256, 3), dim3(256), 0, stream>>>(x, wth, wtl, qfh, qfl, kfh, kfl, vfr);
  flash_kernel<<<dim3(1024), dim3(256), 0, stream>>>(qfh, qfl, kfh, kfl, vfr, out);
}

// Round 16
// 120.338 us; speedup vs baseline: 1.0738x; 1.0738x over previous
//
#include <hip/hip_runtime.h>

// Head: x[8,2048,1024] fp32 -> q,k,v = x@w{q,k,v} -> causal softmax(q k^T * sqrt(128)) @ v
// Precision: bf16x3 split-GEMM for Q/K projections and QK^T (fp32-grade scores), bf16 V/PV.
// Q/K/V stored in MFMA-fragment-major layout (64-lane x 16B frags contiguous); flash reads
// operands straight from L2 (coalesced 1KB frags). Softmax in log2 domain (log2e in wq).
// Flash is split-s two-pass (even/odd 256-tiles -> 2 blocks/q-group, partials merged by a
// light second kernel) when ws_size permits; else single-pass fallback.

#define NB 8
#define NT 2048
#define NE 1024
#define ND 128

typedef unsigned short U16;
typedef unsigned int U32;
typedef __attribute__((ext_vector_type(8))) short vbf8;  // 8 bf16 (4 VGPR) MFMA frag
typedef __attribute__((ext_vector_type(4))) float vf4;   // MFMA 16x16 accum

#define EXP2F(x) __builtin_amdgcn_exp2f(x)  // v_exp_f32: D = 2^S0

__device__ __forceinline__ U16 f2bf(float f) {  // RNE fp32->bf16
  U32 u = __builtin_bit_cast(U32, f);
  u += 0x7fffu + ((u >> 16) & 1u);
  return (U16)(u >> 16);
}
__device__ __forceinline__ float bf2f(U16 h) {
  U32 u = ((U32)h) << 16;
  return __builtin_bit_cast(float, u);
}
__device__ __forceinline__ void gl_lds16(const void* g, void* l) {
  __builtin_amdgcn_global_load_lds((__attribute__((address_space(1))) void*)g,
                                   (__attribute__((address_space(3))) void*)l, 16, 0, 0);
}

// ---------------- kernel 1: weight transpose + split (fold sqrt(128)*log2e into wq) ---
__global__ void wsplit_kernel(const float* __restrict__ wq, const float* __restrict__ wk,
                              const float* __restrict__ wv, U16* __restrict__ wth,
                              U16* __restrict__ wtl) {
  int id = blockIdx.x * 256 + threadIdx.x;  // [0, 384*1024)
  if (id >= 384 * 1024) return;
  int n = id >> 10, e = id & 1023;
  float v;
  if (n < 128)      v = wq[e * 128 + n] * 16.322231701033217f;  // sqrt(128)*log2(e)
  else if (n < 256) v = wk[e * 128 + (n - 128)];
  else              v = wv[e * 128 + (n - 256)];
  U16 h = f2bf(v);
  wth[id] = h;
  wtl[id] = f2bf(v - bf2f(h));
}

// ---------------- kernel 2: QKV projection, bf16x3 split GEMM ------------------------
// Tile 64(M)x128(N), BK=64. grid (256, 3): y 0->Q(hi/lo frag) 1->K(hi/lo frag) 2->V(frag).
// GEMM-loop LDS layout [row][8 granules of 16B], granule XOR-swizzled by (row&7) both sides.
// A-tile float4 loads for step t+1 issued under compute of t (T14 async-stage split).
__global__ __launch_bounds__(256, 3) void qkv_kernel(
    const float* __restrict__ x, const U16* __restrict__ wth, const U16* __restrict__ wtl,
    U16* __restrict__ qfh, U16* __restrict__ qfl, U16* __restrict__ kfh,
    U16* __restrict__ kfl, U16* __restrict__ vf) {
  __shared__ __align__(16) char smem[49152];  // Ah/Al 8KB each, Bh/Bl 16KB each
  char* Ah = smem;
  char* Al = smem + 8192;
  char* Bh = smem + 16384;
  char* Bl = smem + 32768;

  const int tid = threadIdx.x;
  const int w = tid >> 6, lane = tid & 63;
  const int fr = lane & 15, fq = lane >> 4;
  const int m0 = blockIdx.x * 64;
  const int nt = blockIdx.y;
  const U16* bh_src = wth + nt * (128 * 1024);
  const U16* bl_src = wtl + nt * (128 * 1024);

  const vf4 vzero = {0.f, 0.f, 0.f, 0.f};
  vf4 acc[2][4];
#pragma unroll
  for (int i = 0; i < 2; ++i)
#pragma unroll
    for (int j = 0; j < 4; ++j) acc[i][j] = vzero;

  const int wm = (w >> 1) * 32, wn = (w & 1) * 64;  // wave tile 32x64
  const int arow = tid >> 2, ag = tid & 3;          // A stage: 2 granules (ag, ag+4)
  const float* abase = x + (size_t)(m0 + arow) * 1024 + ag * 8;

  float v0[8], v1[8];  // A prefetch registers (tile t+1 loaded under compute of t)
  {
    const float* s = abase;
    ((float4*)v0)[0] = *(const float4*)(s);
    ((float4*)v0)[1] = *(const float4*)(s + 4);
    ((float4*)v1)[0] = *(const float4*)(s + 32);
    ((float4*)v1)[1] = *(const float4*)(s + 36);
  }

  for (int k0 = 0; k0 < 1024; k0 += 64) {
    // --- async-stage B hi(/lo) [128 n][64 k], source-granule pre-swizzled ---
#pragma unroll
    for (int p = 0; p < 4; ++p) {
      const int g = p * 256 + tid;
      const int row = g >> 3, c = g & 7;
      const int sc = c ^ (row & 7);
      const int ldsb = (p * 256 + w * 64) * 16;  // wave-uniform granule base
      gl_lds16(bh_src + row * 1024 + k0 + sc * 8, Bh + ldsb);
      if (nt < 2) gl_lds16(bl_src + row * 1024 + k0 + sc * 8, Bl + ldsb);
    }
    // --- split prefetched A regs -> swizzled LDS writes ---
    {
      vbf8 h0, l0, h1, l1;
#pragma unroll
      for (int i = 0; i < 8; ++i) {
        U16 a = f2bf(v0[i]);
        h0[i] = (short)a; l0[i] = (short)f2bf(v0[i] - bf2f(a));
        U16 b = f2bf(v1[i]);
        h1[i] = (short)b; l1[i] = (short)f2bf(v1[i] - bf2f(b));
      }
      const int sw = arow & 7;
      *(vbf8*)(Ah + arow * 128 + ((ag ^ sw) << 4))       = h0;
      *(vbf8*)(Ah + arow * 128 + (((ag + 4) ^ sw) << 4)) = h1;
      if (nt < 2) {
        *(vbf8*)(Al + arow * 128 + ((ag ^ sw) << 4))       = l0;
        *(vbf8*)(Al + arow * 128 + (((ag + 4) ^ sw) << 4)) = l1;
      }
    }
    __syncthreads();

    // --- issue A loads for t+1 (latency hidden under the MFMA block below) ---
    if (k0 + 64 < 1024) {
      const float* s = abase + k0 + 64;
      ((float4*)v0)[0] = *(const float4*)(s);
      ((float4*)v0)[1] = *(const float4*)(s + 4);
      ((float4*)v1)[0] = *(const float4*)(s + 32);
      ((float4*)v1)[1] = *(const float4*)(s + 36);
    }

    if (nt < 2) {
#pragma unroll
      for (int kc = 0; kc < 2; ++kc) {
        vbf8 a_h[2], a_l[2], b_h[4], b_l[4];
#pragma unroll
        for (int i = 0; i < 2; ++i) {
          const int row = wm + i * 16 + fr;
          const int off = row * 128 + (((kc * 4 + fq) ^ (row & 7)) << 4);
          a_h[i] = *(const vbf8*)(Ah + off);
          a_l[i] = *(const vbf8*)(Al + off);
        }
#pragma unroll
        for (int j = 0; j < 4; ++j) {
          const int row = wn + j * 16 + fr;
          const int off = row * 128 + (((kc * 4 + fq) ^ (row & 7)) << 4);
          b_h[j] = *(const vbf8*)(Bh + off);
          b_l[j] = *(const vbf8*)(Bl + off);
        }
#pragma unroll
        for (int i = 0; i < 2; ++i)
#pragma unroll
          for (int j = 0; j < 4; ++j) {  // (Ah+Al)(Bh+Bl) dropping Al*Bl
            acc[i][j] = __builtin_amdgcn_mfma_f32_16x16x32_bf16(a_h[i], b_h[j], acc[i][j], 0, 0, 0);
            acc[i][j] = __builtin_amdgcn_mfma_f32_16x16x32_bf16(a_h[i], b_l[j], acc[i][j], 0, 0, 0);
            acc[i][j] = __builtin_amdgcn_mfma_f32_16x16x32_bf16(a_l[i], b_h[j], acc[i][j], 0, 0, 0);
          }
      }
    } else {  // V: hh only
#pragma unroll
      for (int kc = 0; kc < 2; ++kc) {
        vbf8 a_h[2], b_h[4];
#pragma unroll
        for (int i = 0; i < 2; ++i) {
          const int row = wm + i * 16 + fr;
          a_h[i] = *(const vbf8*)(Ah + row * 128 + (((kc * 4 + fq) ^ (row & 7)) << 4));
        }
#pragma unroll
        for (int j = 0; j < 4; ++j) {
          const int row = wn + j * 16 + fr;
          b_h[j] = *(const vbf8*)(Bh + row * 128 + (((kc * 4 + fq) ^ (row & 7)) << 4));
        }
#pragma unroll
        for (int i = 0; i < 2; ++i)
#pragma unroll
          for (int j = 0; j < 4; ++j)
            acc[i][j] = __builtin_amdgcn_mfma_f32_16x16x32_bf16(a_h[i], b_h[j], acc[i][j], 0, 0, 0);
      }
    }
    __syncthreads();
  }

  const int b = m0 >> 11;
  if (nt < 2) {  // Q or K: C -> padded LDS -> hi/lo fragment-major layout
    U16* tlh = (U16*)smem;            // [64][132]
    U16* tll = (U16*)(smem + 16896);  // [64][132]
#pragma unroll
    for (int i = 0; i < 2; ++i)
#pragma unroll
      for (int j = 0; j < 4; ++j)
#pragma unroll
        for (int r = 0; r < 4; ++r) {
          const int ml = wm + i * 16 + fq * 4 + r;   // C/D: row=(lane>>4)*4+r
          const int col = wn + j * 16 + fr;          //      col=lane&15
          const float val = acc[i][j][r];
          const U16 h = f2bf(val);
          tlh[ml * 132 + col] = h;
          tll[ml * 132 + col] = f2bf(val - bf2f(h));
        }
    __syncthreads();
    U16* dh = (nt == 0) ? qfh : kfh;
    U16* dl = (nt == 0) ? qfl : kfl;
    const int g0 = (m0 & 2047) >> 4;
#pragma unroll
    for (int p = 0; p < 4; ++p) {
      const int idx = p * 256 + tid;               // 0..1023
      const int gl = idx >> 8, kc = (idx >> 6) & 3, ln = idx & 63;
      const int row = gl * 16 + (ln & 15);
      const int colc = kc * 32 + (ln >> 4) * 8;
      const size_t o = (((size_t)b * 128 + g0 + gl) * 4 + kc) * 512 + ln * 8;
      *(vbf8*)(dh + o) = *(const vbf8*)(tlh + row * 132 + colc);
      *(vbf8*)(dl + o) = *(const vbf8*)(tll + row * 132 + colc);
    }
  } else {  // V: C -> padded LDS transpose -> fragment-major layout
    U16* tl = (U16*)smem;  // [128 d][68 s-local]
#pragma unroll
    for (int i = 0; i < 2; ++i)
#pragma unroll
      for (int j = 0; j < 4; ++j)
#pragma unroll
        for (int r = 0; r < 4; ++r) {
          const int ml = wm + i * 16 + fq * 4 + r;
          const int col = wn + j * 16 + fr;
          tl[col * 68 + ml] = f2bf(acc[i][j][r]);
        }
    __syncthreads();
    const int sc0 = (m0 & 2047) >> 5;  // 2 s-chunks per block
#pragma unroll
    for (int p = 0; p < 4; ++p) {
      const int idx = p * 256 + tid;               // 0..1023
      const int df = idx >> 7, sc = (idx >> 6) & 1, ln = idx & 63;
      const int d = df * 16 + (ln & 15);
      const int sl = sc * 32 + (ln >> 4) * 8;
      const size_t o = (((size_t)b * 8 + df) * 64 + (sc0 + sc)) * 512 + ln * 8;
      *(vbf8*)(vf + o) = *(const vbf8*)(tl + d * 68 + sl);
    }
  }
}

// ================= flash core (shared by split and single-pass) =======================
// SPLIT=1: grid 2048, block bid2 -> (bid=bid2>>1, half=bid2&1); processes 256-tiles
//   T = half, half+2, ...; writes UNNORMALIZED partial (O[16][128], M[16], L[16]) to
//   part + ((bb*128+g)*2+half)*2112 floats. SPLIT=0: grid 1024, normalizes + writes out.
template <int SPLIT>
__global__ __launch_bounds__(256, 3) void flash_kernel_t(
    const U16* __restrict__ qfh, const U16* __restrict__ qfl,
    const U16* __restrict__ kfh, const U16* __restrict__ kfl,
    const U16* __restrict__ vf, float* __restrict__ out, float* __restrict__ part) {
  __shared__ __align__(16) char smem[25088];
  // loop phase:  per-wave P buffer [16][72] U16 at smem + w*2304 (9216 B total)
  // merge phase: O_d [3][16][128] f32 (24576) | m_s [4][16] | l_s [4][16]

  const int tid = threadIdx.x;
  const int w = tid >> 6, lane = tid & 63;
  const int fr = lane & 15, fq = lane >> 4;
  const int sq = w;
  const int bid2 = blockIdx.x;
  const int half = SPLIT ? (bid2 & 1) : 0;
  const int bid = SPLIT ? (bid2 >> 1) : bid2;
  const int bb = bid & 7;            // batch -> XCD round-robin locality
  const int jj = bid >> 3;           // 0..127
  const int g = (jj < 64) ? (127 - jj) : (jj - 64);  // LPT: heavy first, light backfill
  const int q0g = g * 16;

  // hoisted Q A-frags (coalesced 1KB frag reads)
  vbf8 q_h[4], q_l[4];
  {
    const U16* qb = qfh + ((size_t)bb * 128 + g) * 2048 + lane * 8;
    const U16* qlb = qfl + ((size_t)bb * 128 + g) * 2048 + lane * 8;
#pragma unroll
    for (int kc = 0; kc < 4; ++kc) {
      q_h[kc] = *(const vbf8*)(qb + kc * 512);
      q_l[kc] = *(const vbf8*)(qlb + kc * 512);
    }
  }

  // K frags: [b][sfi=s/16][kc][512]; wave's frags sfi = T*16 + sq*4 + sf
  const U16* khp = kfh + (size_t)bb * 262144 + (size_t)(sq * 4) * 2048 + lane * 8
                   + (size_t)half * 32768;
  const U16* klp = kfl + (size_t)bb * 262144 + (size_t)(sq * 4) * 2048 + lane * 8
                   + (size_t)half * 32768;
  // V frags: [b][df][sc=s/32][512]; wave's chunks sc = T*8 + sq*2 + c
  const U16* vfp = vf + (size_t)bb * 262144 + (size_t)(sq * 2) * 512 + lane * 8
                   + (size_t)half * 4096;
  U16* pw = (U16*)(smem + w * 2304);  // [16][72]

  const vf4 vzero = {0.f, 0.f, 0.f, 0.f};
  vf4 oacc[8];
#pragma unroll
  for (int i = 0; i < 8; ++i) oacc[i] = vzero;
  float m_r[4], l_r[4];
#pragma unroll
  for (int r = 0; r < 4; ++r) { m_r[r] = -__builtin_inff(); l_r[r] = 0.f; }

  const int lim = q0g + 15 - sq * 64;          // wave skips tiles fully past diagonal
  const int ntw = (lim >= 0) ? ((lim >> 8) + 1) : 0;
  const int my_n = SPLIT ? ((ntw > half) ? ((ntw - half + 1) >> 1) : 0) : ntw;
  const int tstep = SPLIT ? 2 : 1;

  for (int it = 0; it < my_n; ++it) {
    const int T = half + it * tstep;
    // S = Q K^T (bf16x3): 4 s-frags x 4 kc x 3 = 48 MFMAs, K frags straight from L2
    vf4 sacc[4] = {vzero, vzero, vzero, vzero};
    __builtin_amdgcn_s_setprio(1);
#pragma unroll
    for (int sf = 0; sf < 4; ++sf) {
#pragma unroll
      for (int kc = 0; kc < 4; ++kc) {
        const vbf8 kh_r = *(const vbf8*)(khp + sf * 2048 + kc * 512);
        const vbf8 kl_r = *(const vbf8*)(klp + sf * 2048 + kc * 512);
        sacc[sf] = __builtin_amdgcn_mfma_f32_16x16x32_bf16(q_h[kc], kh_r, sacc[sf], 0, 0, 0);
        sacc[sf] = __builtin_amdgcn_mfma_f32_16x16x32_bf16(q_h[kc], kl_r, sacc[sf], 0, 0, 0);
        sacc[sf] = __builtin_amdgcn_mfma_f32_16x16x32_bf16(q_l[kc], kh_r, sacc[sf], 0, 0, 0);
      }
    }
    __builtin_amdgcn_s_setprio(0);

    if (T == ntw - 1) {  // causal mask (each wave's last tile is its only partial one)
#pragma unroll
      for (int sf = 0; sf < 4; ++sf) {
        const int s_g = T * 256 + sq * 64 + sf * 16 + fr;
#pragma unroll
        for (int r = 0; r < 4; ++r)
          if (s_g > q0g + fq * 4 + r) sacc[sf][r] = -__builtin_inff();
      }
    }

    // online softmax (log2 domain) over the wave's 64 s-cols (16-lane fr groups)
    float tmax[4];
#pragma unroll
    for (int r = 0; r < 4; ++r)
      tmax[r] = fmaxf(fmaxf(sacc[0][r], sacc[1][r]), fmaxf(sacc[2][r], sacc[3][r]));
#pragma unroll
    for (int off = 1; off < 16; off <<= 1)
#pragma unroll
      for (int r = 0; r < 4; ++r) tmax[r] = fmaxf(tmax[r], __shfl_xor(tmax[r], off, 64));

    // V frag loads (16) issued here; hidden under exp/psum/P-LDS below
    vbf8 vreg[8][2];
#pragma unroll
    for (int df = 0; df < 8; ++df) {
      vreg[df][0] = *(const vbf8*)(vfp + df * 32768);
      vreg[df][1] = *(const vbf8*)(vfp + df * 32768 + 512);
    }

    bool need = false;
    float mne[4];
#pragma unroll
    for (int r = 0; r < 4; ++r) {
      need |= (tmax[r] > m_r[r]);
      const float mn = fmaxf(m_r[r], tmax[r]);
      mne[r] = (mn == -__builtin_inff()) ? 0.f : mn;  // fully-masked guard
    }
    if (__any(need)) {  // rescale only when some row's max grew (exact)
#pragma unroll
      for (int r = 0; r < 4; ++r) {
        const float alpha = EXP2F(m_r[r] - mne[r]);  // m_r=-inf -> 0
        l_r[r] *= alpha;
        m_r[r] = fmaxf(m_r[r], tmax[r]);
#pragma unroll
        for (int i = 0; i < 8; ++i) oacc[i][r] *= alpha;
      }
    }

    float psum[4];
    U16 pb[4][4];
#pragma unroll
    for (int sf = 0; sf < 4; ++sf)
#pragma unroll
      for (int r = 0; r < 4; ++r) {
        const float pv = EXP2F(sacc[sf][r] - mne[r]);
        psum[r] = (sf == 0) ? pv : (psum[r] + pv);
        pb[sf][r] = f2bf(pv);
      }
#pragma unroll
    for (int off = 1; off < 16; off <<= 1)
#pragma unroll
      for (int r = 0; r < 4; ++r) psum[r] += __shfl_xor(psum[r], off, 64);
#pragma unroll
    for (int r = 0; r < 4; ++r) l_r[r] += psum[r];

    // P (C-layout) -> wave-private LDS -> two A-frags (16x64 tile)
#pragma unroll
    for (int sf = 0; sf < 4; ++sf)
#pragma unroll
      for (int r = 0; r < 4; ++r) pw[(fq * 4 + r) * 72 + sf * 16 + fr] = pb[sf][r];
    asm volatile("s_waitcnt lgkmcnt(0)" ::: "memory");
    const vbf8 pf0 = *(const vbf8*)(pw + fr * 72 + fq * 8);
    const vbf8 pf1 = *(const vbf8*)(pw + fr * 72 + 32 + fq * 8);

    // PV: 16 MFMAs from prefetched V regs
    __builtin_amdgcn_s_setprio(1);
#pragma unroll
    for (int df = 0; df < 8; ++df) {
      oacc[df] = __builtin_amdgcn_mfma_f32_16x16x32_bf16(pf0, vreg[df][0], oacc[df], 0, 0, 0);
      oacc[df] = __builtin_amdgcn_mfma_f32_16x16x32_bf16(pf1, vreg[df][1], oacc[df], 0, 0, 0);
    }
    __builtin_amdgcn_s_setprio(0);

    khp += 32768 * tstep; klp += 32768 * tstep; vfp += 4096 * tstep;
  }

  // ---- 4-way s-quarter merge (only barriers in the kernel) ----
  __syncthreads();
  float* O_d = (float*)smem;                 // [3][16][128]
  float* m_s = (float*)(smem + 24576);       // [4][16]
  float* l_s = (float*)(smem + 24832);       // [4][16]
  if (sq > 0) {
#pragma unroll
    for (int i = 0; i < 8; ++i)
#pragma unroll
      for (int r = 0; r < 4; ++r)
        O_d[((sq - 1) * 16 + fq * 4 + r) * 128 + i * 16 + fr] = oacc[i][r];
  }
  if (fr == 0) {
#pragma unroll
    for (int r = 0; r < 4; ++r) {
      m_s[sq * 16 + fq * 4 + r] = m_r[r];
      l_s[sq * 16 + fq * 4 + r] = l_r[r];
    }
  }
  __syncthreads();
  if (sq == 0) {
    float* pO = SPLIT ? (part + ((size_t)(bb * 128 + g) * 2 + half) * 2112) : (float*)0;
#pragma unroll
    for (int r = 0; r < 4; ++r) {
      const int row = fq * 4 + r;
      float mv[4];
      float M = -__builtin_inff();
#pragma unroll
      for (int p = 0; p < 4; ++p) {
        mv[p] = m_s[p * 16 + row];
        M = fmaxf(M, mv[p]);
      }
      const float Mne = (M == -__builtin_inff()) ? 0.f : M;  // all-masked guard (half=1)
      float wgt[4], denom = 0.f;
#pragma unroll
      for (int p = 0; p < 4; ++p) {
        wgt[p] = EXP2F(mv[p] - Mne);           // -inf -> 0
        denom += wgt[p] * l_s[p * 16 + row];
      }
      if (SPLIT) {
#pragma unroll
        for (int i = 0; i < 8; ++i) {
          float o = wgt[0] * oacc[i][r];
#pragma unroll
          for (int p = 1; p < 4; ++p)
            o += wgt[p] * O_d[((p - 1) * 16 + row) * 128 + i * 16 + fr];
          pO[row * 128 + i * 16 + fr] = o;     // unnormalized numerator
        }
        if (fr == 0) {
          pO[2048 + row] = M;
          pO[2064 + row] = denom;              // combined L
        }
      } else {
        const float inv = 1.f / denom;         // sq0 always has the diagonal -> denom>0
#pragma unroll
        for (int i = 0; i < 8; ++i) {
          float o = wgt[0] * oacc[i][r];
#pragma unroll
          for (int p = 1; p < 4; ++p)
            o += wgt[p] * O_d[((p - 1) * 16 + row) * 128 + i * 16 + fr];
          out[(size_t)(bb * 2048 + q0g + row) * 128 + i * 16 + fr] = o * inv;
        }
      }
    }
  }
}

// ---------------- kernel 4: two-partial merge (split path only) ----------------------
__global__ __launch_bounds__(256) void fmerge_kernel(const float* __restrict__ part,
                                                     float* __restrict__ out) {
  const int tid = threadIdx.x;
  const int rg = blockIdx.x * 16 + (tid >> 4);   // global row 0..16383
  const int c8 = (tid & 15) * 8;
  const int b = rg >> 11, rb = rg & 2047, g = rb >> 4, r16 = rb & 15;
  const float* p0 = part + ((size_t)(b * 128 + g) * 2 + 0) * 2112;
  const float* p1 = part + ((size_t)(b * 128 + g) * 2 + 1) * 2112;
  const float M0 = p0[2048 + r16], M1 = p1[2048 + r16];
  const float L0 = p0[2064 + r16], L1 = p1[2064 + r16];
  const float M = fmaxf(M0, M1);                 // finite: half 0 always has tile 0
  const float e0 = EXP2F(M0 - M);
  const float e1 = EXP2F(M1 - M);                // M1=-inf -> 0
  const float inv = 1.f / (L0 * e0 + L1 * e1);
  const float* a0 = p0 + r16 * 128 + c8;
  const float* a1 = p1 + r16 * 128 + c8;
  float* o = out + (size_t)rg * 128 + c8;
#pragma unroll
  for (int j = 0; j < 8; ++j) o[j] = (a0[j] * e0 + a1[j] * e1) * inv;
}

// ---------------- host ----------------------------------------------------------------
extern "C" void kernel_launch(void* const* d_in, const int* in_sizes, int n_in, void* d_out,
                              int out_size, void* d_ws, size_t ws_size, hipStream_t stream) {
  const float* x = (const float*)d_in[0];
  const float* wq = (const float*)d_in[1];
  const float* wk = (const float*)d_in[2];
  const float* wv = (const float*)d_in[3];
  char* ws = (char*)d_ws;
  U16* wth = (U16*)(ws);              // 768 KB
  U16* wtl = (U16*)(ws + 786432);     // 768 KB
  U16* qfh = (U16*)(ws + 1572864);    // 4 MiB each below (fragment-major)
  U16* qfl = (U16*)(ws + 5767168);
  U16* kfh = (U16*)(ws + 9961472);
  U16* kfl = (U16*)(ws + 14155776);
  U16* vfr = (U16*)(ws + 18350080);
  float* part = (float*)(ws + 22544384);  // 2048 partials x 2112 floats = 17.3 MB
  float* out = (float*)d_out;

  wsplit_kernel<<<dim3(1536), dim3(256), 0, stream>>>(wq, wk, wv, wth, wtl);
  qkv_kernel<<<dim3(256, 3), dim3(256), 0, stream>>>(x, wth, wtl, qfh, qfl, kfh, kfl, vfr);

  const size_t need = 22544384ull + 2048ull * 2112ull * 4ull;
  if (ws_size >= need) {
    flash_kernel_t<1><<<dim3(2048), dim3(256), 0, stream>>>(qfh, qfl, kfh, kfl, vfr, out, part);
    fmerge_kernel<<<dim3(1024), dim3(256), 0, stream>>>(part, out);
  } else {
    flash_kernel_t<0><<<dim3(1024), dim3(256), 0, stream>>>(qfh, qfl, kfh, kfl, vfr, out, part);
  }
}

// Round 17
// 91.559 us; speedup vs baseline: 1.4113x; 1.3143x over previous
//
#include <hip/hip_runtime.h>

// Head: x[8,2048,1024] fp32 -> q,k,v = x@w{q,k,v} -> causal softmax(q k^T * sqrt(128)) @ v
// Precision: bf16x3 split-GEMM for Q/K projections and QK^T (fp32-grade scores), bf16 V/PV.
// Q/K/V stored in MFMA-fragment-major layout (64-lane x 16B frags contiguous); flash reads
// operands straight from L2 (coalesced 1KB frags). Softmax in log2 domain (log2e in wq).
// Flash PV runs in two V-chunks reusing one vreg[8] (32 fewer live regs -> 3 waves/SIMD
// on the unified VGPR+AGPR file).

#define NB 8
#define NT 2048
#define NE 1024
#define ND 128

typedef unsigned short U16;
typedef unsigned int U32;
typedef __attribute__((ext_vector_type(8))) short vbf8;  // 8 bf16 (4 VGPR) MFMA frag
typedef __attribute__((ext_vector_type(4))) float vf4;   // MFMA 16x16 accum

#define EXP2F(x) __builtin_amdgcn_exp2f(x)  // v_exp_f32: D = 2^S0

__device__ __forceinline__ U16 f2bf(float f) {  // RNE fp32->bf16
  U32 u = __builtin_bit_cast(U32, f);
  u += 0x7fffu + ((u >> 16) & 1u);
  return (U16)(u >> 16);
}
__device__ __forceinline__ float bf2f(U16 h) {
  U32 u = ((U32)h) << 16;
  return __builtin_bit_cast(float, u);
}
__device__ __forceinline__ void gl_lds16(const void* g, void* l) {
  __builtin_amdgcn_global_load_lds((__attribute__((address_space(1))) void*)g,
                                   (__attribute__((address_space(3))) void*)l, 16, 0, 0);
}

// ---------------- kernel 1: weight transpose + split (fold sqrt(128)*log2e into wq) ---
__global__ void wsplit_kernel(const float* __restrict__ wq, const float* __restrict__ wk,
                              const float* __restrict__ wv, U16* __restrict__ wth,
                              U16* __restrict__ wtl) {
  int id = blockIdx.x * 256 + threadIdx.x;  // [0, 384*1024)
  if (id >= 384 * 1024) return;
  int n = id >> 10, e = id & 1023;
  float v;
  if (n < 128)      v = wq[e * 128 + n] * 16.322231701033217f;  // sqrt(128)*log2(e)
  else if (n < 256) v = wk[e * 128 + (n - 128)];
  else              v = wv[e * 128 + (n - 256)];
  U16 h = f2bf(v);
  wth[id] = h;
  wtl[id] = f2bf(v - bf2f(h));
}

// ---------------- kernel 2: QKV projection, bf16x3 split GEMM ------------------------
// Tile 64(M)x128(N), BK=64. grid (256, 3): y 0->Q(hi/lo frag) 1->K(hi/lo frag) 2->V(frag).
// GEMM-loop LDS layout [row][8 granules of 16B], granule XOR-swizzled by (row&7) both sides.
// A-tile float4 loads for step t+1 issued under compute of t (T14 async-stage split).
__global__ __launch_bounds__(256, 3) void qkv_kernel(
    const float* __restrict__ x, const U16* __restrict__ wth, const U16* __restrict__ wtl,
    U16* __restrict__ qfh, U16* __restrict__ qfl, U16* __restrict__ kfh,
    U16* __restrict__ kfl, U16* __restrict__ vf) {
  __shared__ __align__(16) char smem[49152];  // Ah/Al 8KB each, Bh/Bl 16KB each
  char* Ah = smem;
  char* Al = smem + 8192;
  char* Bh = smem + 16384;
  char* Bl = smem + 32768;

  const int tid = threadIdx.x;
  const int w = tid >> 6, lane = tid & 63;
  const int fr = lane & 15, fq = lane >> 4;
  const int m0 = blockIdx.x * 64;
  const int nt = blockIdx.y;
  const U16* bh_src = wth + nt * (128 * 1024);
  const U16* bl_src = wtl + nt * (128 * 1024);

  const vf4 vzero = {0.f, 0.f, 0.f, 0.f};
  vf4 acc[2][4];
#pragma unroll
  for (int i = 0; i < 2; ++i)
#pragma unroll
    for (int j = 0; j < 4; ++j) acc[i][j] = vzero;

  const int wm = (w >> 1) * 32, wn = (w & 1) * 64;  // wave tile 32x64
  const int arow = tid >> 2, ag = tid & 3;          // A stage: 2 granules (ag, ag+4)
  const float* abase = x + (size_t)(m0 + arow) * 1024 + ag * 8;

  float v0[8], v1[8];  // A prefetch registers (tile t+1 loaded under compute of t)
  {
    const float* s = abase;
    ((float4*)v0)[0] = *(const float4*)(s);
    ((float4*)v0)[1] = *(const float4*)(s + 4);
    ((float4*)v1)[0] = *(const float4*)(s + 32);
    ((float4*)v1)[1] = *(const float4*)(s + 36);
  }

  for (int k0 = 0; k0 < 1024; k0 += 64) {
    // --- async-stage B hi(/lo) [128 n][64 k], source-granule pre-swizzled ---
#pragma unroll
    for (int p = 0; p < 4; ++p) {
      const int g = p * 256 + tid;
      const int row = g >> 3, c = g & 7;
      const int sc = c ^ (row & 7);
      const int ldsb = (p * 256 + w * 64) * 16;  // wave-uniform granule base
      gl_lds16(bh_src + row * 1024 + k0 + sc * 8, Bh + ldsb);
      if (nt < 2) gl_lds16(bl_src + row * 1024 + k0 + sc * 8, Bl + ldsb);
    }
    // --- split prefetched A regs -> swizzled LDS writes ---
    {
      vbf8 h0, l0, h1, l1;
#pragma unroll
      for (int i = 0; i < 8; ++i) {
        U16 a = f2bf(v0[i]);
        h0[i] = (short)a; l0[i] = (short)f2bf(v0[i] - bf2f(a));
        U16 b = f2bf(v1[i]);
        h1[i] = (short)b; l1[i] = (short)f2bf(v1[i] - bf2f(b));
      }
      const int sw = arow & 7;
      *(vbf8*)(Ah + arow * 128 + ((ag ^ sw) << 4))       = h0;
      *(vbf8*)(Ah + arow * 128 + (((ag + 4) ^ sw) << 4)) = h1;
      if (nt < 2) {
        *(vbf8*)(Al + arow * 128 + ((ag ^ sw) << 4))       = l0;
        *(vbf8*)(Al + arow * 128 + (((ag + 4) ^ sw) << 4)) = l1;
      }
    }
    __syncthreads();

    // --- issue A loads for t+1 (latency hidden under the MFMA block below) ---
    if (k0 + 64 < 1024) {
      const float* s = abase + k0 + 64;
      ((float4*)v0)[0] = *(const float4*)(s);
      ((float4*)v0)[1] = *(const float4*)(s + 4);
      ((float4*)v1)[0] = *(const float4*)(s + 32);
      ((float4*)v1)[1] = *(const float4*)(s + 36);
    }

    if (nt < 2) {
#pragma unroll
      for (int kc = 0; kc < 2; ++kc) {
        vbf8 a_h[2], a_l[2], b_h[4], b_l[4];
#pragma unroll
        for (int i = 0; i < 2; ++i) {
          const int row = wm + i * 16 + fr;
          const int off = row * 128 + (((kc * 4 + fq) ^ (row & 7)) << 4);
          a_h[i] = *(const vbf8*)(Ah + off);
          a_l[i] = *(const vbf8*)(Al + off);
        }
#pragma unroll
        for (int j = 0; j < 4; ++j) {
          const int row = wn + j * 16 + fr;
          const int off = row * 128 + (((kc * 4 + fq) ^ (row & 7)) << 4);
          b_h[j] = *(const vbf8*)(Bh + off);
          b_l[j] = *(const vbf8*)(Bl + off);
        }
#pragma unroll
        for (int i = 0; i < 2; ++i)
#pragma unroll
          for (int j = 0; j < 4; ++j) {  // (Ah+Al)(Bh+Bl) dropping Al*Bl
            acc[i][j] = __builtin_amdgcn_mfma_f32_16x16x32_bf16(a_h[i], b_h[j], acc[i][j], 0, 0, 0);
            acc[i][j] = __builtin_amdgcn_mfma_f32_16x16x32_bf16(a_h[i], b_l[j], acc[i][j], 0, 0, 0);
            acc[i][j] = __builtin_amdgcn_mfma_f32_16x16x32_bf16(a_l[i], b_h[j], acc[i][j], 0, 0, 0);
          }
      }
    } else {  // V: hh only
#pragma unroll
      for (int kc = 0; kc < 2; ++kc) {
        vbf8 a_h[2], b_h[4];
#pragma unroll
        for (int i = 0; i < 2; ++i) {
          const int row = wm + i * 16 + fr;
          a_h[i] = *(const vbf8*)(Ah + row * 128 + (((kc * 4 + fq) ^ (row & 7)) << 4));
        }
#pragma unroll
        for (int j = 0; j < 4; ++j) {
          const int row = wn + j * 16 + fr;
          b_h[j] = *(const vbf8*)(Bh + row * 128 + (((kc * 4 + fq) ^ (row & 7)) << 4));
        }
#pragma unroll
        for (int i = 0; i < 2; ++i)
#pragma unroll
          for (int j = 0; j < 4; ++j)
            acc[i][j] = __builtin_amdgcn_mfma_f32_16x16x32_bf16(a_h[i], b_h[j], acc[i][j], 0, 0, 0);
      }
    }
    __syncthreads();
  }

  const int b = m0 >> 11;
  if (nt < 2) {  // Q or K: C -> padded LDS -> hi/lo fragment-major layout
    U16* tlh = (U16*)smem;            // [64][132]
    U16* tll = (U16*)(smem + 16896);  // [64][132]
#pragma unroll
    for (int i = 0; i < 2; ++i)
#pragma unroll
      for (int j = 0; j < 4; ++j)
#pragma unroll
        for (int r = 0; r < 4; ++r) {
          const int ml = wm + i * 16 + fq * 4 + r;   // C/D: row=(lane>>4)*4+r
          const int col = wn + j * 16 + fr;          //      col=lane&15
          const float val = acc[i][j][r];
          const U16 h = f2bf(val);
          tlh[ml * 132 + col] = h;
          tll[ml * 132 + col] = f2bf(val - bf2f(h));
        }
    __syncthreads();
    U16* dh = (nt == 0) ? qfh : kfh;
    U16* dl = (nt == 0) ? qfl : kfl;
    const int g0 = (m0 & 2047) >> 4;
#pragma unroll
    for (int p = 0; p < 4; ++p) {
      const int idx = p * 256 + tid;               // 0..1023
      const int gl = idx >> 8, kc = (idx >> 6) & 3, ln = idx & 63;
      const int row = gl * 16 + (ln & 15);
      const int colc = kc * 32 + (ln >> 4) * 8;
      const size_t o = (((size_t)b * 128 + g0 + gl) * 4 + kc) * 512 + ln * 8;
      *(vbf8*)(dh + o) = *(const vbf8*)(tlh + row * 132 + colc);
      *(vbf8*)(dl + o) = *(const vbf8*)(tll + row * 132 + colc);
    }
  } else {  // V: C -> padded LDS transpose -> fragment-major layout
    U16* tl = (U16*)smem;  // [128 d][68 s-local]
#pragma unroll
    for (int i = 0; i < 2; ++i)
#pragma unroll
      for (int j = 0; j < 4; ++j)
#pragma unroll
        for (int r = 0; r < 4; ++r) {
          const int ml = wm + i * 16 + fq * 4 + r;
          const int col = wn + j * 16 + fr;
          tl[col * 68 + ml] = f2bf(acc[i][j][r]);
        }
    __syncthreads();
    const int sc0 = (m0 & 2047) >> 5;  // 2 s-chunks per block
#pragma unroll
    for (int p = 0; p < 4; ++p) {
      const int idx = p * 256 + tid;               // 0..1023
      const int df = idx >> 7, sc = (idx >> 6) & 1, ln = idx & 63;
      const int d = df * 16 + (ln & 15);
      const int sl = sc * 32 + (ln >> 4) * 8;
      const size_t o = (((size_t)b * 8 + df) * 64 + (sc0 + sc)) * 512 + ln * 8;
      *(vbf8*)(vf + o) = *(const vbf8*)(tl + d * 68 + sl);
    }
  }
}

// ---------------- kernel 3: causal flash attention, SBLK=256 frag streaming ----------
// grid 1024 = 8 b x 128 q-groups of 16 rows; block 256 thr = 4 waves, wave sq=0..3
// owns the sq-quarter (64 s-cols = 4 frags) of each 256-wide s-tile. K/V frags read
// directly from L2 (coalesced 1KB), zero staging, zero in-loop barriers. Softmax in
// log2 domain; O-rescale skipped (exact) when no row max grows. PV in two V-chunks
// reusing ONE vreg[8] (saves 32 live regs on the unified VGPR+AGPR file -> 3 waves/
// SIMD; sched_barrier stops the compiler hoisting chunk-B loads). 4-way merge at end.
// g mapping: heavy-desc then light-asc (LPT). min-waves 3 ((256,4) spills, r13).
__global__ __launch_bounds__(256, 3) void flash_kernel(
    const U16* __restrict__ qfh, const U16* __restrict__ qfl,
    const U16* __restrict__ kfh, const U16* __restrict__ kfl,
    const U16* __restrict__ vf, float* __restrict__ out) {
  __shared__ __align__(16) char smem[25088];
  // loop phase:  per-wave P buffer [16][72] U16 at smem + w*2304 (9216 B total)
  // merge phase: O_d [3][16][128] f32 (24576) | m_s [4][16] | l_s [4][16]

  const int tid = threadIdx.x;
  const int w = tid >> 6, lane = tid & 63;
  const int fr = lane & 15, fq = lane >> 4;
  const int sq = w;
  const int bid = blockIdx.x;
  const int bb = bid & 7;            // batch -> XCD round-robin locality
  const int jj = bid >> 3;           // 0..127
  const int g = (jj < 64) ? (127 - jj) : (jj - 64);  // LPT: heavy first, light backfill
  const int q0g = g * 16;

  // hoisted Q A-frags (coalesced 1KB frag reads)
  vbf8 q_h[4], q_l[4];
  {
    const U16* qb = qfh + ((size_t)bb * 128 + g) * 2048 + lane * 8;
    const U16* qlb = qfl + ((size_t)bb * 128 + g) * 2048 + lane * 8;
#pragma unroll
    for (int kc = 0; kc < 4; ++kc) {
      q_h[kc] = *(const vbf8*)(qb + kc * 512);
      q_l[kc] = *(const vbf8*)(qlb + kc * 512);
    }
  }

  // K frags: [b][sfi=s/16][kc][512]; wave's frags sfi = T*16 + sq*4 + sf
  const U16* khp = kfh + (size_t)bb * 262144 + (size_t)(sq * 4) * 2048 + lane * 8;
  const U16* klp = kfl + (size_t)bb * 262144 + (size_t)(sq * 4) * 2048 + lane * 8;
  // V frags: [b][df][sc=s/32][512]; wave's chunks sc = T*8 + sq*2 + c
  const U16* vfp = vf + (size_t)bb * 262144 + (size_t)(sq * 2) * 512 + lane * 8;
  U16* pw = (U16*)(smem + w * 2304);  // [16][72]

  const vf4 vzero = {0.f, 0.f, 0.f, 0.f};
  vf4 oacc[8];
#pragma unroll
  for (int i = 0; i < 8; ++i) oacc[i] = vzero;
  float m_r[4], l_r[4];
#pragma unroll
  for (int r = 0; r < 4; ++r) { m_r[r] = -__builtin_inff(); l_r[r] = 0.f; }

  const int lim = q0g + 15 - sq * 64;          // wave skips tiles fully past diagonal
  const int ntw = (lim >= 0) ? ((lim >> 8) + 1) : 0;

  for (int T = 0; T < ntw; ++T) {
    // S = Q K^T (bf16x3): 4 s-frags x 4 kc x 3 = 48 MFMAs, K frags straight from L2
    vf4 sacc[4] = {vzero, vzero, vzero, vzero};
    __builtin_amdgcn_s_setprio(1);
#pragma unroll
    for (int sf = 0; sf < 4; ++sf) {
#pragma unroll
      for (int kc = 0; kc < 4; ++kc) {
        const vbf8 kh_r = *(const vbf8*)(khp + sf * 2048 + kc * 512);
        const vbf8 kl_r = *(const vbf8*)(klp + sf * 2048 + kc * 512);
        sacc[sf] = __builtin_amdgcn_mfma_f32_16x16x32_bf16(q_h[kc], kh_r, sacc[sf], 0, 0, 0);
        sacc[sf] = __builtin_amdgcn_mfma_f32_16x16x32_bf16(q_h[kc], kl_r, sacc[sf], 0, 0, 0);
        sacc[sf] = __builtin_amdgcn_mfma_f32_16x16x32_bf16(q_l[kc], kh_r, sacc[sf], 0, 0, 0);
      }
    }
    __builtin_amdgcn_s_setprio(0);

    if (T == ntw - 1) {  // causal mask (each wave's last tile is its only partial one)
#pragma unroll
      for (int sf = 0; sf < 4; ++sf) {
        const int s_g = T * 256 + sq * 64 + sf * 16 + fr;
#pragma unroll
        for (int r = 0; r < 4; ++r)
          if (s_g > q0g + fq * 4 + r) sacc[sf][r] = -__builtin_inff();
      }
    }

    // online softmax (log2 domain) over the wave's 64 s-cols (16-lane fr groups)
    float tmax[4];
#pragma unroll
    for (int r = 0; r < 4; ++r)
      tmax[r] = fmaxf(fmaxf(sacc[0][r], sacc[1][r]), fmaxf(sacc[2][r], sacc[3][r]));
#pragma unroll
    for (int off = 1; off < 16; off <<= 1)
#pragma unroll
      for (int r = 0; r < 4; ++r) tmax[r] = fmaxf(tmax[r], __shfl_xor(tmax[r], off, 64));

    // V chunk-A loads (8) issued here; hidden under exp/psum/P-LDS below
    vbf8 vreg[8];
#pragma unroll
    for (int df = 0; df < 8; ++df) vreg[df] = *(const vbf8*)(vfp + df * 32768);

    bool need = false;
    float mne[4];
#pragma unroll
    for (int r = 0; r < 4; ++r) {
      need |= (tmax[r] > m_r[r]);
      const float mn = fmaxf(m_r[r], tmax[r]);
      mne[r] = (mn == -__builtin_inff()) ? 0.f : mn;  // fully-masked guard
    }
    if (__any(need)) {  // rescale only when some row's max grew (exact)
#pragma unroll
      for (int r = 0; r < 4; ++r) {
        const float alpha = EXP2F(m_r[r] - mne[r]);  // m_r=-inf -> 0
        l_r[r] *= alpha;
        m_r[r] = fmaxf(m_r[r], tmax[r]);
#pragma unroll
        for (int i = 0; i < 8; ++i) oacc[i][r] *= alpha;
      }
    }

    float psum[4];
    U16 pb[4][4];
#pragma unroll
    for (int sf = 0; sf < 4; ++sf)
#pragma unroll
      for (int r = 0; r < 4; ++r) {
        const float pv = EXP2F(sacc[sf][r] - mne[r]);
        psum[r] = (sf == 0) ? pv : (psum[r] + pv);
        pb[sf][r] = f2bf(pv);
      }
#pragma unroll
    for (int off = 1; off < 16; off <<= 1)
#pragma unroll
      for (int r = 0; r < 4; ++r) psum[r] += __shfl_xor(psum[r], off, 64);
#pragma unroll
    for (int r = 0; r < 4; ++r) l_r[r] += psum[r];

    // P (C-layout) -> wave-private LDS -> two A-frags (16x64 tile)
#pragma unroll
    for (int sf = 0; sf < 4; ++sf)
#pragma unroll
      for (int r = 0; r < 4; ++r) pw[(fq * 4 + r) * 72 + sf * 16 + fr] = pb[sf][r];
    asm volatile("s_waitcnt lgkmcnt(0)" ::: "memory");
    const vbf8 pf0 = *(const vbf8*)(pw + fr * 72 + fq * 8);
    const vbf8 pf1 = *(const vbf8*)(pw + fr * 72 + 32 + fq * 8);

    // PV chunk A: 8 MFMAs from prefetched V regs
    __builtin_amdgcn_s_setprio(1);
#pragma unroll
    for (int df = 0; df < 8; ++df)
      oacc[df] = __builtin_amdgcn_mfma_f32_16x16x32_bf16(pf0, vreg[df], oacc[df], 0, 0, 0);
    __builtin_amdgcn_s_setprio(0);
    __builtin_amdgcn_sched_barrier(0);  // keep chunk-B loads below (reg reuse of vreg)

    // PV chunk B: reload vreg with the second 32-s chunk, 8 MFMAs
#pragma unroll
    for (int df = 0; df < 8; ++df) vreg[df] = *(const vbf8*)(vfp + df * 32768 + 512);
    __builtin_amdgcn_s_setprio(1);
#pragma unroll
    for (int df = 0; df < 8; ++df)
      oacc[df] = __builtin_amdgcn_mfma_f32_16x16x32_bf16(pf1, vreg[df], oacc[df], 0, 0, 0);
    __builtin_amdgcn_s_setprio(0);

    khp += 32768; klp += 32768; vfp += 4096;  // next 256-wide tile
  }

  // ---- 4-way s-quarter merge (only barriers in the kernel) ----
  __syncthreads();
  float* O_d = (float*)smem;                 // [3][16][128]
  float* m_s = (float*)(smem + 24576);       // [4][16]
  float* l_s = (float*)(smem + 24832);       // [4][16]
  if (sq > 0) {
#pragma unroll
    for (int i = 0; i < 8; ++i)
#pragma unroll
      for (int r = 0; r < 4; ++r)
        O_d[((sq - 1) * 16 + fq * 4 + r) * 128 + i * 16 + fr] = oacc[i][r];
  }
  if (fr == 0) {
#pragma unroll
    for (int r = 0; r < 4; ++r) {
      m_s[sq * 16 + fq * 4 + r] = m_r[r];
      l_s[sq * 16 + fq * 4 + r] = l_r[r];
    }
  }
  __syncthreads();
  if (sq == 0) {
#pragma unroll
    for (int r = 0; r < 4; ++r) {
      const int row = fq * 4 + r;
      float mv[4];
      float M = -__builtin_inff();
#pragma unroll
      for (int p = 0; p < 4; ++p) {
        mv[p] = m_s[p * 16 + row];
        M = fmaxf(M, mv[p]);
      }
      float wgt[4], denom = 0.f;
#pragma unroll
      for (int p = 0; p < 4; ++p) {
        wgt[p] = EXP2F(mv[p] - M);             // -inf (idle/masked quarter) -> 0
        denom += wgt[p] * l_s[p * 16 + row];
      }
      const float inv = 1.f / denom;           // sq0 always has the diagonal -> denom>0
#pragma unroll
      for (int i = 0; i < 8; ++i) {
        float o = wgt[0] * oacc[i][r];
#pragma unroll
        for (int p = 1; p < 4; ++p)
          o += wgt[p] * O_d[((p - 1) * 16 + row) * 128 + i * 16 + fr];
        out[(size_t)(bb * 2048 + q0g + row) * 128 + i * 16 + fr] = o * inv;
      }
    }
  }
}

// ---------------- host ----------------------------------------------------------------
extern "C" void kernel_launch(void* const* d_in, const int* in_sizes, int n_in, void* d_out,
                              int out_size, void* d_ws, size_t ws_size, hipStream_t stream) {
  const float* x = (const float*)d_in[0];
  const float* wq = (const float*)d_in[1];
  const float* wk = (const float*)d_in[2];
  const float* wv = (const float*)d_in[3];
  char* ws = (char*)d_ws;
  U16* wth = (U16*)(ws);              // 768 KB
  U16* wtl = (U16*)(ws + 786432);     // 768 KB
  U16* qfh = (U16*)(ws + 1572864);    // 4 MiB each below (fragment-major)
  U16* qfl = (U16*)(ws + 5767168);
  U16* kfh = (U16*)(ws + 9961472);
  U16* kfl = (U16*)(ws + 14155776);
  U16* vfr = (U16*)(ws + 18350080);
  float* out = (float*)d_out;

  wsplit_kernel<<<dim3(1536), dim3(256), 0, stream>>>(wq, wk, wv, wth, wtl);
  qkv_kernel<<<dim3(256, 3), dim3(256), 0, stream>>>(x, wth, wtl, qfh, qfl, kfh, kfl, vfr);
  flash_kernel<<<dim3(1024), dim3(256), 0, stream>>>(qfh, qfl, kfh, kfl, vfr, out);
}